// Round 9
// baseline (125.440 us; speedup 1.0000x reference)
//
#include <hip/hip_runtime.h>
#include <hip/hip_bf16.h>
#include <math.h>

#define NB 16
#define C_IN 64
#define C_OUT 64
#define HH 128
#define WW 128
#define MAX_SHIFT 4.0f

typedef __attribute__((ext_vector_type(8))) short bf16x8;
typedef __attribute__((ext_vector_type(4))) float f32x4;
typedef __attribute__((ext_vector_type(4))) unsigned int u32x4;

__device__ inline unsigned short bf16_rne(float f) {
    unsigned u = __builtin_bit_cast(unsigned, f);
    u += 0x7fffu + ((u >> 16) & 1u);
    return (unsigned short)(u >> 16);
}
__device__ inline unsigned pack_bf16x2(float lo, float hi) {
    unsigned ul = __builtin_bit_cast(unsigned, lo);
    unsigned uh = __builtin_bit_cast(unsigned, hi);
    ul += 0x7fffu + ((ul >> 16) & 1u);
    uh += 0x7fffu + ((uh >> 16) & 1u);
    return (ul >> 16) | (uh & 0xffff0000u);
}

// =====================================================================
// xsp layout: [n][h][wh2][kb6][wl64][k32] bf16
//   k = p*64 + c ; kb = k/32 ; per (n,h,wh) block: 24KB contiguous
// =====================================================================
#define RSTR 202   // u16 stride per w in LDS (odd dword stride 101 -> conflict-free writes)

__global__ __launch_bounds__(256)
void shift_pow(const float* __restrict__ x, const float* __restrict__ shifts,
               unsigned short* __restrict__ xsp) {
    __shared__ unsigned short row[64 * RSTR];   // 25,856 B
    __shared__ float s_fx[C_IN], s_fy[C_IN];
    __shared__ int s_dx[C_IN], s_dy[C_IN];

    int b = blockIdx.x;            // [n16][h128][wh2]
    int wh = b & 1;
    int h  = (b >> 1) & 127;
    int n  = b >> 8;
    int tid = threadIdx.x;
    int wv = tid >> 6;             // 0..3
    int l  = tid & 63;

    if (tid < C_IN) {
        float sx = shifts[2 * tid] * MAX_SHIFT;
        float sy = shifts[2 * tid + 1] * MAX_SHIFT;
        float fx0 = floorf(sx), fy0 = floorf(sy);
        s_dx[tid] = (int)fx0; s_dy[tid] = (int)fy0;
        s_fx[tid] = sx - fx0;  s_fy[tid] = sy - fy0;
    }
    __syncthreads();

    const float* xn = x + (size_t)n * (C_IN * HH * WW);
    int w = wh * 64 + l;
    unsigned short* rw = row + l * RSTR;

    #pragma unroll 4
    for (int it = 0; it < 16; ++it) {
        int c = it * 4 + wv;                       // wave-uniform
        int dx = s_dx[c], dy = s_dy[c];
        float fx = s_fx[c], fy = s_fy[c];
        const float* xp = xn + (size_t)c * (HH * WW);
        int y0 = h + dy, y1 = y0 + 1;
        bool vy0 = ((unsigned)y0 < (unsigned)HH);
        bool vy1 = ((unsigned)y1 < (unsigned)HH);
        const float* r0 = xp + y0 * WW;
        const float* r1 = xp + y1 * WW;

        int x0 = w + dx, x1 = x0 + 1;
        bool vx0 = ((unsigned)x0 < (unsigned)WW);
        bool vx1 = ((unsigned)x1 < (unsigned)WW);
        float v00 = (vy0 && vx0) ? r0[x0] : 0.f;
        float v01 = (vy0 && vx1) ? r0[x1] : 0.f;
        float v10 = (vy1 && vx0) ? r1[x0] : 0.f;
        float v11 = (vy1 && vx1) ? r1[x1] : 0.f;
        float v = (1.f - fy) * ((1.f - fx) * v00 + fx * v01)
                + fy * ((1.f - fx) * v10 + fx * v11);
        float v2 = v * v, v3 = v2 * v;
        rw[c]       = bf16_rne(v);
        rw[64 + c]  = bf16_rne(v2);
        rw[128 + c] = bf16_rne(v3);
    }
    __syncthreads();

    // writeout: 6144 u32 = 24KB FULLY CONTIGUOUS per (n,h,wh)
    //   o32 = (kb*64 + wl)*16 + k4
    const unsigned* rp = (const unsigned*)row;
    unsigned* dst = (unsigned*)xsp + ((size_t)((n * HH + h) * 2 + wh) * 6144);
    #pragma unroll
    for (int itw = 0; itw < 24; ++itw) {
        int o32 = itw * 256 + tid;        // 0..6143
        int kb = o32 >> 10;
        int rem = o32 & 1023;
        int wl = rem >> 4;
        int k4 = rem & 15;
        dst[o32] = rp[wl * (RSTR / 2) + kb * 16 + k4];
    }
}

// =====================================================================
// weight prep: [t9][kb6][mf4][lane64][e8] bf16
// =====================================================================
__global__ void prep_w2(const float* __restrict__ w, unsigned short* __restrict__ wbuf) {
    int id = blockIdx.x * 256 + threadIdx.x;   // < 110592
    int e = id & 7;
    int l = (id >> 3) & 63;
    int f = id >> 9;          // 0..215
    int mf = f & 3;
    int f2 = f >> 2;          // 0..53
    int kb = f2 % 6;
    int t  = f2 / 6;
    int k  = kb * 32 + (l >> 4) * 8 + e;   // 0..191
    int p  = k >> 6;
    int c  = k & 63;
    int co = mf * 16 + (l & 15);
    wbuf[id] = bf16_rne(w[(co * 192 + p * 64 + c) * 9 + t]);
}

// =====================================================================
// PASS 2: implicit-GEMM conv. 16x16 output tile, grid 1024.
//   LDS tile [18*18 px][44 u16] (88B stride -> conflict-free b128 reads)
// =====================================================================
#define CSTR 44    // u16 per px (32 payload + 12 pad); 88 B

__global__ __launch_bounds__(256, 2)
void conv2(const unsigned short* __restrict__ xsp,
           const unsigned short* __restrict__ wbuf,
           const float* __restrict__ bias,
           float* __restrict__ out) {
    __shared__ unsigned short tile[324 * CSTR];   // 28,512 B

    int bid = blockIdx.x;
    int wg = (bid & 7) * 128 + (bid >> 3);   // bijective XCD swizzle (1024 = 8*128)
    int n  = wg >> 6;
    int t6 = wg & 63;
    int i0 = (t6 >> 3) * 16;
    int j0 = (t6 & 7) * 16;

    int tid = threadIdx.x;
    int l  = tid & 63;
    int wv = tid >> 6;
    int lm = l & 15;
    int lg = l >> 4;

    f32x4 acc[4][4];      // [mf][nf=row]
    #pragma unroll
    for (int mf = 0; mf < 4; ++mf) {
        #pragma unroll
        for (int r = 0; r < 4; ++r) {
            float bv = bias[mf * 16 + lg * 4 + r];
            #pragma unroll
            for (int nf = 0; nf < 4; ++nf) acc[mf][nf][r] = bv;
        }
    }

    // per-image stride: HH*2 blocks x 12288 u16 (= 6144 u32) each
    const unsigned short* xb = xsp + (size_t)n * (HH * 2 * 12288);
    int lds_base = (wv * 4 * 18 + lm) * 88 + lg * 16;   // bytes

    #pragma unroll 1
    for (int kb = 0; kb < 6; ++kb) {
        __syncthreads();
        // ---- stage: 18 rows x 18 px x 64 B ----
        // addr(gi,gj,kb,sub) = xb + ((gi*2 + (gj>>6))*6 + kb)*2048 + (gj&63)*32 + sub*8   (u16)
        #pragma unroll
        for (int it = 0; it < 6; ++it) {
            int ch = it * 256 + tid;          // 0..1295 (18*18*4)
            if (ch < 1296) {
                int rr  = ch / 72;
                int rem = ch - rr * 72;
                int pxr = rem >> 2, sub = rem & 3;
                int gi = i0 - 1 + rr, gj = j0 - 1 + pxr;
                u32x4 d = {0, 0, 0, 0};
                if ((unsigned)gi < (unsigned)HH && (unsigned)gj < (unsigned)WW)
                    d = *(const u32x4*)(xb + ((size_t)((gi * 2 + (gj >> 6)) * 6 + kb)) * 2048
                                           + (gj & 63) * 32 + sub * 8);
                *(u32x4*)((char*)tile + (rr * 18 + pxr) * 88 + sub * 16) = d;
            }
        }
        __syncthreads();

        // ---- compute: 9 taps x 4 nf x 4 mf MFMAs ----
        bf16x8 Af[4];
        #pragma unroll
        for (int mf = 0; mf < 4; ++mf)
            Af[mf] = *(const bf16x8*)(wbuf + (size_t)((0 * 6 + kb) * 4 + mf) * 512 + l * 8);

        #pragma unroll 1
        for (int t = 0; t < 9; ++t) {
            bf16x8 Afn[4];
            int tn = (t < 8) ? t + 1 : t;
            #pragma unroll
            for (int mf = 0; mf < 4; ++mf)
                Afn[mf] = *(const bf16x8*)(wbuf + (size_t)((tn * 6 + kb) * 4 + mf) * 512 + l * 8);

            int ky = t / 3, kx = t - ky * 3;
            #pragma unroll
            for (int nf = 0; nf < 4; ++nf) {
                int off = lds_base + ((nf + ky) * 18 + kx) * 88;
                bf16x8 bfrag = *(const bf16x8*)((const char*)tile + off);
                #pragma unroll
                for (int mf = 0; mf < 4; ++mf)
                    acc[mf][nf] = __builtin_amdgcn_mfma_f32_16x16x32_bf16(Af[mf], bfrag, acc[mf][nf], 0, 0, 0);
            }
            #pragma unroll
            for (int mf = 0; mf < 4; ++mf) Af[mf] = Afn[mf];
        }
    }

    // ---- epilogue ----
    #pragma unroll
    for (int mf = 0; mf < 4; ++mf) {
        #pragma unroll
        for (int nf = 0; nf < 4; ++nf) {
            int rowi = i0 + wv * 4 + nf;
            int col = j0 + lm;
            #pragma unroll
            for (int r = 0; r < 4; ++r) {
                int co = mf * 16 + lg * 4 + r;
                out[(((size_t)n * C_OUT + co) * HH + rowi) * WW + col] = acc[mf][nf][r];
            }
        }
    }
}

// =====================================================================
// Fallback tier: fused kernel (only if ws too small for xsp)
// =====================================================================
#define TH 16
#define TW 32
#define PR (TH + 2)
#define PC (TW + 2)
#define NPX (PR * PC)
#define CHP 40

__global__ void prep_w_fused(const float* __restrict__ w, unsigned short* __restrict__ wbuf) {
    int id = blockIdx.x * 256 + threadIdx.x;
    int e = id & 7;
    int l = (id >> 3) & 63;
    int frag = id >> 9;
    int mf = frag & 3;
    int f2 = frag >> 2;
    int t = f2 % 9;
    int f3 = f2 / 9;
    int p = f3 % 3;
    int kg = f3 / 3;
    int co = mf * 16 + (l & 15);
    int ci = kg * 32 + (l >> 4) * 8 + e;
    wbuf[id] = bf16_rne(w[(co * 192 + p * 64 + ci) * 9 + t]);
}

__global__ __launch_bounds__(256, 2)
void conv_fused(const float* __restrict__ x,
                const float* __restrict__ shifts,
                const unsigned short* __restrict__ wbuf,
                const float* __restrict__ bias,
                float* __restrict__ out) {
    __shared__ unsigned short tile[NPX * CHP];
    __shared__ float s_fx[C_IN], s_fy[C_IN];
    __shared__ int s_dx[C_IN], s_dy[C_IN];

    int bid = blockIdx.x;
    int wg = (bid & 7) * 64 + (bid >> 3);
    int n  = wg >> 5;
    int t5 = wg & 31;
    int i0 = (t5 >> 2) * TH;
    int j0 = (t5 & 3) * TW;

    int tid = threadIdx.x;
    int l  = tid & 63;
    int wv = tid >> 6;
    int lm = l & 15;
    int lg = l >> 4;

    if (tid < C_IN) {
        float sx = shifts[2 * tid] * MAX_SHIFT;
        float sy = shifts[2 * tid + 1] * MAX_SHIFT;
        float fx0 = floorf(sx), fy0 = floorf(sy);
        s_dx[tid] = (int)fx0; s_dy[tid] = (int)fy0;
        s_fx[tid] = sx - fx0;  s_fy[tid] = sy - fy0;
    }

    f32x4 acc[4][8];
    #pragma unroll
    for (int mf = 0; mf < 4; ++mf) {
        #pragma unroll
        for (int r = 0; r < 4; ++r) {
            float b = bias[mf * 16 + lg * 4 + r];
            #pragma unroll
            for (int nf = 0; nf < 8; ++nf) acc[mf][nf][r] = b;
        }
    }

    const float* xn = x + n * (C_IN * HH * WW);
    const char* ldsb = (const char*)tile;
    int lds_base = ((wv * 4) * PC + lm) * (CHP * 2) + lg * 16;

    #pragma unroll 1
    for (int kg = 0; kg < 2; ++kg) {
        __syncthreads();
        for (int e = tid; e < NPX * 32; e += 256) {
            int cl = e / NPX;
            int px = e - cl * NPX;
            int r  = px / PC;
            int c  = px - r * PC;
            int ci = kg * 32 + cl;
            int gi = i0 - 1 + r;
            int gj = j0 - 1 + c;
            float v = 0.f;
            if (gi >= 0 && gi < HH && gj >= 0 && gj < WW) {
                int y0 = gi + s_dy[ci], y1 = y0 + 1;
                int x0 = gj + s_dx[ci], x1 = x0 + 1;
                float fx = s_fx[ci], fy = s_fy[ci];
                const float* xp = xn + ci * (HH * WW);
                float v00 = (y0 >= 0 && y0 < HH && x0 >= 0 && x0 < WW) ? xp[y0 * WW + x0] : 0.f;
                float v01 = (y0 >= 0 && y0 < HH && x1 >= 0 && x1 < WW) ? xp[y0 * WW + x1] : 0.f;
                float v10 = (y1 >= 0 && y1 < HH && x0 >= 0 && x0 < WW) ? xp[y1 * WW + x0] : 0.f;
                float v11 = (y1 >= 0 && y1 < HH && x1 >= 0 && x1 < WW) ? xp[y1 * WW + x1] : 0.f;
                v = (1.f - fy) * ((1.f - fx) * v00 + fx * v01)
                  + fy * ((1.f - fx) * v10 + fx * v11);
            }
            tile[px * CHP + cl] = bf16_rne(v);
        }
        __syncthreads();

        const unsigned short* wk = wbuf + kg * (3 * 9 * 4 * 512);
        #pragma unroll 1
        for (int t = 0; t < 9; ++t) {
            int ky = t / 3, kx = t - ky * 3;
            bf16x8 Af[3][4];
            #pragma unroll
            for (int p = 0; p < 3; ++p)
                #pragma unroll
                for (int mf = 0; mf < 4; ++mf)
                    Af[p][mf] = *(const bf16x8*)(wk + ((size_t)((p * 9 + t) * 4 + mf)) * 512 + l * 8);

            int toff = (ky * PC + kx) * (CHP * 2);
            #pragma unroll
            for (int nf = 0; nf < 8; ++nf) {
                int rl = nf >> 1, cb = nf & 1;
                int off = lds_base + toff + (rl * PC + cb * 16) * (CHP * 2);
                bf16x8 b1 = *(const bf16x8*)(ldsb + off);
                u32x4 bu = __builtin_bit_cast(u32x4, b1);
                unsigned d2[4], d3[4];
                #pragma unroll
                for (int q = 0; q < 4; ++q) {
                    float fl = __builtin_bit_cast(float, bu[q] << 16);
                    float fh = __builtin_bit_cast(float, bu[q] & 0xffff0000u);
                    float fl2 = fl * fl, fh2 = fh * fh;
                    float fl3 = fl2 * fl, fh3 = fh2 * fh;
                    d2[q] = pack_bf16x2(fl2, fh2);
                    d3[q] = pack_bf16x2(fl3, fh3);
                }
                bf16x8 b2 = __builtin_bit_cast(bf16x8, (u32x4){d2[0], d2[1], d2[2], d2[3]});
                bf16x8 b3 = __builtin_bit_cast(bf16x8, (u32x4){d3[0], d3[1], d3[2], d3[3]});
                #pragma unroll
                for (int mf = 0; mf < 4; ++mf)
                    acc[mf][nf] = __builtin_amdgcn_mfma_f32_16x16x32_bf16(Af[0][mf], b1, acc[mf][nf], 0, 0, 0);
                #pragma unroll
                for (int mf = 0; mf < 4; ++mf)
                    acc[mf][nf] = __builtin_amdgcn_mfma_f32_16x16x32_bf16(Af[1][mf], b2, acc[mf][nf], 0, 0, 0);
                #pragma unroll
                for (int mf = 0; mf < 4; ++mf)
                    acc[mf][nf] = __builtin_amdgcn_mfma_f32_16x16x32_bf16(Af[2][mf], b3, acc[mf][nf], 0, 0, 0);
            }
        }
    }

    #pragma unroll
    for (int mf = 0; mf < 4; ++mf) {
        #pragma unroll
        for (int nf = 0; nf < 8; ++nf) {
            int rl = nf >> 1, cb = nf & 1;
            int row = i0 + wv * 4 + rl;
            int col = j0 + cb * 16 + lm;
            #pragma unroll
            for (int r = 0; r < 4; ++r) {
                int co = mf * 16 + lg * 4 + r;
                out[((n * C_OUT + co) * HH + row) * WW + col] = acc[mf][nf][r];
            }
        }
    }
}

extern "C" void kernel_launch(void* const* d_in, const int* in_sizes, int n_in,
                              void* d_out, int out_size, void* d_ws, size_t ws_size,
                              hipStream_t stream) {
    (void)in_sizes; (void)n_in; (void)out_size;
    const float* x      = (const float*)d_in[0];
    const float* weight = (const float*)d_in[1];
    const float* bias   = (const float*)d_in[2];
    const float* shifts = (const float*)d_in[3];
    float* out = (float*)d_out;

    const size_t xsp_elems = (size_t)NB * HH * WW * 192;        // u16 count
    const size_t need2 = xsp_elems * 2 + 110592 * 2;            // ~100.9 MB
    const size_t need1 = 110592 * 2;                            // 216 KB

    if (ws_size >= need2) {
        unsigned short* xsp  = (unsigned short*)d_ws;
        unsigned short* wbuf = xsp + xsp_elems;
        prep_w2<<<432, 256, 0, stream>>>(weight, wbuf);
        shift_pow<<<NB * HH * 2, 256, 0, stream>>>(x, shifts, xsp);
        conv2<<<1024, 256, 0, stream>>>(xsp, wbuf, bias, out);
    } else {
        unsigned short* wbuf = (unsigned short*)d_ws;
        prep_w_fused<<<432, 256, 0, stream>>>(weight, wbuf);
        conv_fused<<<NB * 4 * 4, 256, 0, stream>>>(x, shifts, wbuf, bias, out);
    }
}

// Round 10
// 117.894 us; speedup vs baseline: 1.0640x; 1.0640x over previous
//
#include <hip/hip_runtime.h>
#include <hip/hip_bf16.h>
#include <math.h>

#define NB 16
#define C_IN 64
#define C_OUT 64
#define HH 128
#define WW 128
#define MAX_SHIFT 4.0f

typedef __attribute__((ext_vector_type(8))) short bf16x8;
typedef __attribute__((ext_vector_type(4))) float f32x4;

__device__ inline unsigned short bf16_rne(float f) {
    unsigned u = __builtin_bit_cast(unsigned, f);
    u += 0x7fffu + ((u >> 16) & 1u);
    return (unsigned short)(u >> 16);
}

// =====================================================================
// weight prep: [t9][kb6][mf4][lane64][e8] bf16
//   kb = cg*3 + p  (cg = input-channel group of 32, p = power 0..2)
//   frag lane l elem e: co = mf*16 + (l&15), k(=cl) = (l>>4)*8 + e
// =====================================================================
__global__ void prep_w3(const float* __restrict__ w, unsigned short* __restrict__ wbuf) {
    int id = blockIdx.x * 256 + threadIdx.x;   // < 110592
    int e = id & 7;
    int l = (id >> 3) & 63;
    int f = id >> 9;          // 0..215
    int mf = f & 3;
    int f2 = f >> 2;          // 0..53
    int kb = f2 % 6;
    int t  = f2 / 6;
    int cg = kb / 3;
    int p  = kb - cg * 3;
    int cl = (l >> 4) * 8 + e;             // 0..31
    int co = mf * 16 + (l & 15);
    wbuf[id] = bf16_rne(w[(co * 192 + p * 64 + cg * 32 + cl) * 9 + t]);
}

// =====================================================================
// FUSED kernel: bilinear shift + powers (in staging) + implicit-GEMM conv
//   16x16 output tile, 4 waves, grid 1024 (XCD-swizzled)
//   LDS: [324 px][100 u16] records = [p3][cl32] payload + 4 pad (200 B)
// =====================================================================
#define S_PX 100   // u16 per px record; 200 B (stride/4=50 dw, gcd(50,32)=2 -> spread)

__global__ __launch_bounds__(256, 2)
void conv_f(const float* __restrict__ x,
            const float* __restrict__ shifts,
            const unsigned short* __restrict__ wbuf,
            const float* __restrict__ bias,
            float* __restrict__ out) {
    __shared__ unsigned short tile[324 * S_PX];   // 64,800 B
    __shared__ float s_fx[C_IN], s_fy[C_IN];
    __shared__ int s_dx[C_IN], s_dy[C_IN];

    int bid = blockIdx.x;
    int wg = (bid & 7) * 128 + (bid >> 3);   // bijective XCD swizzle (1024 = 8*128)
    int n  = wg >> 6;
    int t6 = wg & 63;
    int i0 = (t6 >> 3) * 16;
    int j0 = (t6 & 7) * 16;

    int tid = threadIdx.x;
    int l  = tid & 63;
    int wv = tid >> 6;
    int lm = l & 15;
    int lg = l >> 4;

    if (tid < C_IN) {
        float sx = shifts[2 * tid] * MAX_SHIFT;
        float sy = shifts[2 * tid + 1] * MAX_SHIFT;
        float fx0 = floorf(sx), fy0 = floorf(sy);
        s_dx[tid] = (int)fx0; s_dy[tid] = (int)fy0;
        s_fx[tid] = sx - fx0;  s_fy[tid] = sy - fy0;
    }

    f32x4 acc[4][4];      // [mf][nf]
    #pragma unroll
    for (int mf = 0; mf < 4; ++mf) {
        #pragma unroll
        for (int r = 0; r < 4; ++r) {
            float bv = bias[mf * 16 + lg * 4 + r];
            #pragma unroll
            for (int nf = 0; nf < 4; ++nf) acc[mf][nf][r] = bv;
        }
    }

    const float* xn = x + (size_t)n * (C_IN * HH * WW);

    #pragma unroll 1
    for (int cg = 0; cg < 2; ++cg) {
        __syncthreads();   // params ready (cg=0) / prev compute done (cg=1)

        // ---- stage: 9 row-pairs x 18 cols x 32 ch; bilinear + powers ----
        #pragma unroll 2
        for (int it = 0; it < 21; ++it) {
            int item = it * 256 + tid;           // < 5184 = 32*162
            if (item < 5184) {
                int cl  = item / 162;            // 0..31
                int rem = item - cl * 162;
                int rp  = rem / 18;              // 0..8  (row pair)
                int cc  = rem - rp * 18;         // 0..17
                int c   = cg * 32 + cl;
                int dx = s_dx[c], dy = s_dy[c];
                float fx = s_fx[c], fy = s_fy[c];
                const float* xp = xn + (size_t)c * (HH * WW);

                int gj  = j0 - 1 + cc;
                int xx0 = gj + dx, xx1 = xx0 + 1;
                bool vx0 = ((unsigned)xx0 < (unsigned)WW);
                bool vx1 = ((unsigned)xx1 < (unsigned)WW);
                int gi0 = i0 - 1 + rp * 2;       // top output row of the pair
                int y0  = gi0 + dy;              // source rows y0, y0+1, y0+2
                bool vyA = ((unsigned)y0 < (unsigned)HH);
                bool vyB = ((unsigned)(y0 + 1) < (unsigned)HH);
                bool vyC = ((unsigned)(y0 + 2) < (unsigned)HH);
                const float* rA = xp + y0 * WW;
                const float* rB = rA + WW;
                const float* rC = rB + WW;
                float m0 = (vyA && vx0) ? rA[xx0] : 0.f;
                float m1 = (vyA && vx1) ? rA[xx1] : 0.f;
                float m2 = (vyB && vx0) ? rB[xx0] : 0.f;
                float m3 = (vyB && vx1) ? rB[xx1] : 0.f;
                float m4 = (vyC && vx0) ? rC[xx0] : 0.f;
                float m5 = (vyC && vx1) ? rC[xx1] : 0.f;
                float hA = (1.f - fx) * m0 + fx * m1;
                float hB = (1.f - fx) * m2 + fx * m3;   // shared row
                float hC = (1.f - fx) * m4 + fx * m5;
                float vT = (1.f - fy) * hA + fy * hB;
                float vU = (1.f - fy) * hB + fy * hC;
                // conv zero-padding on the SHIFTED map:
                if (!((unsigned)gj < (unsigned)WW))        { vT = 0.f; vU = 0.f; }
                if (!((unsigned)gi0 < (unsigned)HH))       vT = 0.f;
                if (!((unsigned)(gi0 + 1) < (unsigned)HH)) vU = 0.f;

                float t2 = vT * vT, t3 = t2 * vT;
                float u2 = vU * vU, u3 = u2 * vU;
                unsigned short* recT = tile + (rp * 2 * 18 + cc) * S_PX;
                unsigned short* recU = recT + 18 * S_PX;
                recT[cl]      = bf16_rne(vT);
                recT[32 + cl] = bf16_rne(t2);
                recT[64 + cl] = bf16_rne(t3);
                recU[cl]      = bf16_rne(vU);
                recU[32 + cl] = bf16_rne(u2);
                recU[64 + cl] = bf16_rne(u3);
            }
        }
        __syncthreads();

        // ---- compute: 3 powers x 9 taps x 4 nf x 4 mf MFMAs ----
        #pragma unroll 1
        for (int p = 0; p < 3; ++p) {
            int kb = cg * 3 + p;
            bf16x8 Af[4];
            #pragma unroll
            for (int mf = 0; mf < 4; ++mf)
                Af[mf] = *(const bf16x8*)(wbuf + (size_t)((0 * 6 + kb) * 4 + mf) * 512 + l * 8);

            #pragma unroll 1
            for (int t = 0; t < 9; ++t) {
                bf16x8 Afn[4];
                int tn = (t < 8) ? t + 1 : t;
                #pragma unroll
                for (int mf = 0; mf < 4; ++mf)
                    Afn[mf] = *(const bf16x8*)(wbuf + (size_t)((tn * 6 + kb) * 4 + mf) * 512 + l * 8);

                int ky = t / 3, kx = t - ky * 3;
                #pragma unroll
                for (int nf = 0; nf < 4; ++nf) {
                    int off = ((wv * 4 + nf + ky) * 18 + (lm + kx)) * 200 + p * 64 + lg * 16;
                    bf16x8 bfrag = *(const bf16x8*)((const char*)tile + off);
                    #pragma unroll
                    for (int mf = 0; mf < 4; ++mf)
                        acc[mf][nf] = __builtin_amdgcn_mfma_f32_16x16x32_bf16(Af[mf], bfrag, acc[mf][nf], 0, 0, 0);
                }
                #pragma unroll
                for (int mf = 0; mf < 4; ++mf) Af[mf] = Afn[mf];
            }
        }
    }

    // ---- epilogue ----
    #pragma unroll
    for (int mf = 0; mf < 4; ++mf) {
        #pragma unroll
        for (int nf = 0; nf < 4; ++nf) {
            int rowi = i0 + wv * 4 + nf;
            int col = j0 + lm;
            #pragma unroll
            for (int r = 0; r < 4; ++r) {
                int co = mf * 16 + lg * 4 + r;
                out[(((size_t)n * C_OUT + co) * HH + rowi) * WW + col] = acc[mf][nf][r];
            }
        }
    }
}

extern "C" void kernel_launch(void* const* d_in, const int* in_sizes, int n_in,
                              void* d_out, int out_size, void* d_ws, size_t ws_size,
                              hipStream_t stream) {
    (void)in_sizes; (void)n_in; (void)out_size; (void)ws_size;
    const float* x      = (const float*)d_in[0];
    const float* weight = (const float*)d_in[1];
    const float* bias   = (const float*)d_in[2];
    const float* shifts = (const float*)d_in[3];
    float* out = (float*)d_out;

    unsigned short* wbuf = (unsigned short*)d_ws;   // 216 KiB needed
    prep_w3<<<432, 256, 0, stream>>>(weight, wbuf);
    conv_f<<<1024, 256, 0, stream>>>(x, shifts, wbuf, bias, out);
}

// Round 11
// 106.638 us; speedup vs baseline: 1.1763x; 1.1055x over previous
//
#include <hip/hip_runtime.h>
#include <hip/hip_bf16.h>
#include <math.h>

#define NB 16
#define C_IN 64
#define C_OUT 64
#define HH 128
#define WW 128
#define MAX_SHIFT 4.0f

typedef __attribute__((ext_vector_type(8))) short bf16x8;
typedef __attribute__((ext_vector_type(4))) float f32x4;
typedef __attribute__((ext_vector_type(4))) unsigned int u32x4;

__device__ inline unsigned short bf16_rne(float f) {
    unsigned u = __builtin_bit_cast(unsigned, f);
    u += 0x7fffu + ((u >> 16) & 1u);
    return (unsigned short)(u >> 16);
}
__device__ inline unsigned pack_bf16x2(float lo, float hi) {
    unsigned ul = __builtin_bit_cast(unsigned, lo);
    unsigned uh = __builtin_bit_cast(unsigned, hi);
    ul += 0x7fffu + ((ul >> 16) & 1u);
    uh += 0x7fffu + ((uh >> 16) & 1u);
    return (ul >> 16) | (uh & 0xffff0000u);
}

// =====================================================================
// PASS 1: bilinear shift only -> xv[n][h][w][c64] bf16 (32 MB)
//   half-row blocks, tiny LDS (8.4 KB) -> high occupancy
// =====================================================================
#define CPAD 66   // u16 per w in LDS (u32 stride 33, odd -> conflict-free)

__global__ __launch_bounds__(256)
void shift_v(const float* __restrict__ x, const float* __restrict__ shifts,
             unsigned short* __restrict__ xv) {
    __shared__ unsigned short row[64 * CPAD];   // 8,448 B
    __shared__ float s_fx[C_IN], s_fy[C_IN];
    __shared__ int s_dx[C_IN], s_dy[C_IN];

    int b = blockIdx.x;            // [n16][h128][wh2]
    int wh = b & 1;
    int h  = (b >> 1) & 127;
    int n  = b >> 8;
    int tid = threadIdx.x;
    int wv = tid >> 6;
    int l  = tid & 63;

    if (tid < C_IN) {
        float sx = shifts[2 * tid] * MAX_SHIFT;
        float sy = shifts[2 * tid + 1] * MAX_SHIFT;
        float fx0 = floorf(sx), fy0 = floorf(sy);
        s_dx[tid] = (int)fx0; s_dy[tid] = (int)fy0;
        s_fx[tid] = sx - fx0;  s_fy[tid] = sy - fy0;
    }
    __syncthreads();

    const float* xn = x + (size_t)n * (C_IN * HH * WW);
    int w = wh * 64 + l;
    unsigned short* rw = row + l * CPAD;

    #pragma unroll 4
    for (int it = 0; it < 16; ++it) {
        int c = it * 4 + wv;                       // wave-uniform
        int dx = s_dx[c], dy = s_dy[c];
        float fx = s_fx[c], fy = s_fy[c];
        const float* xp = xn + (size_t)c * (HH * WW);
        int y0 = h + dy, y1 = y0 + 1;
        bool vy0 = ((unsigned)y0 < (unsigned)HH);
        bool vy1 = ((unsigned)y1 < (unsigned)HH);
        const float* r0 = xp + y0 * WW;
        const float* r1 = xp + y1 * WW;

        int x0 = w + dx, x1 = x0 + 1;
        bool vx0 = ((unsigned)x0 < (unsigned)WW);
        bool vx1 = ((unsigned)x1 < (unsigned)WW);
        float v00 = (vy0 && vx0) ? r0[x0] : 0.f;
        float v01 = (vy0 && vx1) ? r0[x1] : 0.f;
        float v10 = (vy1 && vx0) ? r1[x0] : 0.f;
        float v11 = (vy1 && vx1) ? r1[x1] : 0.f;
        float v = (1.f - fy) * ((1.f - fx) * v00 + fx * v01)
                + fy * ((1.f - fx) * v10 + fx * v11);
        rw[c] = bf16_rne(v);
    }
    __syncthreads();

    // writeout: 64 w x 32 u32 = 8 KB contiguous per (n,h,wh)
    const unsigned* rp = (const unsigned*)row;
    unsigned* dst = (unsigned*)xv + ((size_t)((n * HH + h) * WW) + wh * 64) * 32;
    #pragma unroll
    for (int itw = 0; itw < 8; ++itw) {
        int o32 = itw * 256 + tid;        // 0..2047
        int wl = o32 >> 5;
        int c4 = o32 & 31;
        dst[o32] = rp[wl * (CPAD / 2) + c4];
    }
}

// =====================================================================
// weight prep: [t9][kb6][mf4][lane64][e8] bf16 ; kb = cg*3 + p, k = cl32
// =====================================================================
__global__ void prep_w3(const float* __restrict__ w, unsigned short* __restrict__ wbuf) {
    int id = blockIdx.x * 256 + threadIdx.x;   // < 110592
    int e = id & 7;
    int l = (id >> 3) & 63;
    int f = id >> 9;          // 0..215
    int mf = f & 3;
    int f2 = f >> 2;          // 0..53
    int kb = f2 % 6;
    int t  = f2 / 6;
    int cg = kb / 3;
    int p  = kb - cg * 3;
    int cl = (l >> 4) * 8 + e;             // 0..31
    int co = mf * 16 + (l & 15);
    wbuf[id] = bf16_rne(w[(co * 192 + p * 64 + cg * 32 + cl) * 9 + t]);
}

// =====================================================================
// PASS 2: conv with powers computed ONCE in staging.
//   16x16 tile, 4 waves, grid 1024. LDS records [324 px][p3][cl32] (200 B)
// =====================================================================
__global__ __launch_bounds__(256, 2)
void conv2b(const unsigned short* __restrict__ xv,
            const unsigned short* __restrict__ wbuf,
            const float* __restrict__ bias,
            float* __restrict__ out) {
    __shared__ unsigned short tile[324 * 100];   // 64,800 B

    int bid = blockIdx.x;
    int wg = (bid & 7) * 128 + (bid >> 3);   // bijective XCD swizzle (1024 = 8*128)
    int n  = wg >> 6;
    int t6 = wg & 63;
    int i0 = (t6 >> 3) * 16;
    int j0 = (t6 & 7) * 16;

    int tid = threadIdx.x;
    int l  = tid & 63;
    int wv = tid >> 6;
    int lm = l & 15;
    int lg = l >> 4;

    f32x4 acc[4][4];      // [mf][nf]
    #pragma unroll
    for (int mf = 0; mf < 4; ++mf) {
        #pragma unroll
        for (int r = 0; r < 4; ++r) {
            float bv = bias[mf * 16 + lg * 4 + r];
            #pragma unroll
            for (int nf = 0; nf < 4; ++nf) acc[mf][nf][r] = bv;
        }
    }

    const unsigned short* xn = xv + (size_t)n * (HH * WW * 64);

    #pragma unroll 1
    for (int cg = 0; cg < 2; ++cg) {
        __syncthreads();
        // ---- stage: 324 px x 8ch-chunks x4 ; coalesced 16B bf16 loads ----
        #pragma unroll
        for (int it = 0; it < 6; ++it) {
            int item = it * 256 + tid;        // < 1296 = 324*4
            if (item < 1296) {
                int px = item >> 2, chunk = item & 3;
                int rr = px / 18;
                int cc = px - rr * 18;
                int gi = i0 - 1 + rr, gj = j0 - 1 + cc;
                u32x4 dv = {0, 0, 0, 0};
                if ((unsigned)gi < (unsigned)HH && (unsigned)gj < (unsigned)WW)
                    dv = *(const u32x4*)(xn + ((size_t)gi * WW + gj) * 64 + cg * 32 + chunk * 8);
                unsigned o2[4], o3[4];
                #pragma unroll
                for (int q = 0; q < 4; ++q) {
                    unsigned u = dv[q];
                    float f0 = __builtin_bit_cast(float, u << 16);
                    float f1 = __builtin_bit_cast(float, u & 0xffff0000u);
                    float p20 = f0 * f0, p21 = f1 * f1;
                    float p30 = p20 * f0, p31 = p21 * f1;
                    o2[q] = pack_bf16x2(p20, p21);
                    o3[q] = pack_bf16x2(p30, p31);
                }
                char* rec = (char*)tile + px * 200 + chunk * 16;
                *(u32x4*)(rec)       = dv;
                *(u32x4*)(rec + 64)  = (u32x4){o2[0], o2[1], o2[2], o2[3]};
                *(u32x4*)(rec + 128) = (u32x4){o3[0], o3[1], o3[2], o3[3]};
            }
        }
        __syncthreads();

        // ---- compute: 3 powers x 9 taps x 4 nf x 4 mf MFMAs ----
        #pragma unroll 1
        for (int p = 0; p < 3; ++p) {
            int kb = cg * 3 + p;
            bf16x8 Af[4];
            #pragma unroll
            for (int mf = 0; mf < 4; ++mf)
                Af[mf] = *(const bf16x8*)(wbuf + (size_t)((0 * 6 + kb) * 4 + mf) * 512 + l * 8);

            #pragma unroll 1
            for (int t = 0; t < 9; ++t) {
                bf16x8 Afn[4];
                int tn = (t < 8) ? t + 1 : t;
                #pragma unroll
                for (int mf = 0; mf < 4; ++mf)
                    Afn[mf] = *(const bf16x8*)(wbuf + (size_t)((tn * 6 + kb) * 4 + mf) * 512 + l * 8);

                int ky = t / 3, kx = t - ky * 3;
                #pragma unroll
                for (int nf = 0; nf < 4; ++nf) {
                    int off = ((wv * 4 + nf + ky) * 18 + (lm + kx)) * 200 + p * 64 + lg * 16;
                    bf16x8 bfrag = *(const bf16x8*)((const char*)tile + off);
                    #pragma unroll
                    for (int mf = 0; mf < 4; ++mf)
                        acc[mf][nf] = __builtin_amdgcn_mfma_f32_16x16x32_bf16(Af[mf], bfrag, acc[mf][nf], 0, 0, 0);
                }
                #pragma unroll
                for (int mf = 0; mf < 4; ++mf) Af[mf] = Afn[mf];
            }
        }
    }

    // ---- epilogue ----
    #pragma unroll
    for (int mf = 0; mf < 4; ++mf) {
        #pragma unroll
        for (int nf = 0; nf < 4; ++nf) {
            int rowi = i0 + wv * 4 + nf;
            int col = j0 + lm;
            #pragma unroll
            for (int r = 0; r < 4; ++r) {
                int co = mf * 16 + lg * 4 + r;
                out[(((size_t)n * C_OUT + co) * HH + rowi) * WW + col] = acc[mf][nf][r];
            }
        }
    }
}

// =====================================================================
// Fallback: fused kernel (round-9), needs only 216 KB ws
// =====================================================================
#define S_PX 100

__global__ __launch_bounds__(256, 2)
void conv_f(const float* __restrict__ x,
            const float* __restrict__ shifts,
            const unsigned short* __restrict__ wbuf,
            const float* __restrict__ bias,
            float* __restrict__ out) {
    __shared__ unsigned short tile[324 * S_PX];
    __shared__ float s_fx[C_IN], s_fy[C_IN];
    __shared__ int s_dx[C_IN], s_dy[C_IN];

    int bid = blockIdx.x;
    int wg = (bid & 7) * 128 + (bid >> 3);
    int n  = wg >> 6;
    int t6 = wg & 63;
    int i0 = (t6 >> 3) * 16;
    int j0 = (t6 & 7) * 16;

    int tid = threadIdx.x;
    int l  = tid & 63;
    int wv = tid >> 6;
    int lm = l & 15;
    int lg = l >> 4;

    if (tid < C_IN) {
        float sx = shifts[2 * tid] * MAX_SHIFT;
        float sy = shifts[2 * tid + 1] * MAX_SHIFT;
        float fx0 = floorf(sx), fy0 = floorf(sy);
        s_dx[tid] = (int)fx0; s_dy[tid] = (int)fy0;
        s_fx[tid] = sx - fx0;  s_fy[tid] = sy - fy0;
    }

    f32x4 acc[4][4];
    #pragma unroll
    for (int mf = 0; mf < 4; ++mf) {
        #pragma unroll
        for (int r = 0; r < 4; ++r) {
            float bv = bias[mf * 16 + lg * 4 + r];
            #pragma unroll
            for (int nf = 0; nf < 4; ++nf) acc[mf][nf][r] = bv;
        }
    }

    const float* xn = x + (size_t)n * (C_IN * HH * WW);

    #pragma unroll 1
    for (int cg = 0; cg < 2; ++cg) {
        __syncthreads();
        #pragma unroll 2
        for (int it = 0; it < 21; ++it) {
            int item = it * 256 + tid;
            if (item < 5184) {
                int cl  = item / 162;
                int rem = item - cl * 162;
                int rp  = rem / 18;
                int cc  = rem - rp * 18;
                int c   = cg * 32 + cl;
                int dx = s_dx[c], dy = s_dy[c];
                float fx = s_fx[c], fy = s_fy[c];
                const float* xp = xn + (size_t)c * (HH * WW);

                int gj  = j0 - 1 + cc;
                int xx0 = gj + dx, xx1 = xx0 + 1;
                bool vx0 = ((unsigned)xx0 < (unsigned)WW);
                bool vx1 = ((unsigned)xx1 < (unsigned)WW);
                int gi0 = i0 - 1 + rp * 2;
                int y0  = gi0 + dy;
                bool vyA = ((unsigned)y0 < (unsigned)HH);
                bool vyB = ((unsigned)(y0 + 1) < (unsigned)HH);
                bool vyC = ((unsigned)(y0 + 2) < (unsigned)HH);
                const float* rA = xp + y0 * WW;
                const float* rB = rA + WW;
                const float* rC = rB + WW;
                float m0 = (vyA && vx0) ? rA[xx0] : 0.f;
                float m1 = (vyA && vx1) ? rA[xx1] : 0.f;
                float m2 = (vyB && vx0) ? rB[xx0] : 0.f;
                float m3 = (vyB && vx1) ? rB[xx1] : 0.f;
                float m4 = (vyC && vx0) ? rC[xx0] : 0.f;
                float m5 = (vyC && vx1) ? rC[xx1] : 0.f;
                float hA = (1.f - fx) * m0 + fx * m1;
                float hB = (1.f - fx) * m2 + fx * m3;
                float hC = (1.f - fx) * m4 + fx * m5;
                float vT = (1.f - fy) * hA + fy * hB;
                float vU = (1.f - fy) * hB + fy * hC;
                if (!((unsigned)gj < (unsigned)WW))        { vT = 0.f; vU = 0.f; }
                if (!((unsigned)gi0 < (unsigned)HH))       vT = 0.f;
                if (!((unsigned)(gi0 + 1) < (unsigned)HH)) vU = 0.f;

                float t2 = vT * vT, t3 = t2 * vT;
                float u2 = vU * vU, u3 = u2 * vU;
                unsigned short* recT = tile + (rp * 2 * 18 + cc) * S_PX;
                unsigned short* recU = recT + 18 * S_PX;
                recT[cl]      = bf16_rne(vT);
                recT[32 + cl] = bf16_rne(t2);
                recT[64 + cl] = bf16_rne(t3);
                recU[cl]      = bf16_rne(vU);
                recU[32 + cl] = bf16_rne(u2);
                recU[64 + cl] = bf16_rne(u3);
            }
        }
        __syncthreads();

        #pragma unroll 1
        for (int p = 0; p < 3; ++p) {
            int kb = cg * 3 + p;
            bf16x8 Af[4];
            #pragma unroll
            for (int mf = 0; mf < 4; ++mf)
                Af[mf] = *(const bf16x8*)(wbuf + (size_t)((0 * 6 + kb) * 4 + mf) * 512 + l * 8);

            #pragma unroll 1
            for (int t = 0; t < 9; ++t) {
                bf16x8 Afn[4];
                int tn = (t < 8) ? t + 1 : t;
                #pragma unroll
                for (int mf = 0; mf < 4; ++mf)
                    Afn[mf] = *(const bf16x8*)(wbuf + (size_t)((tn * 6 + kb) * 4 + mf) * 512 + l * 8);

                int ky = t / 3, kx = t - ky * 3;
                #pragma unroll
                for (int nf = 0; nf < 4; ++nf) {
                    int off = ((wv * 4 + nf + ky) * 18 + (lm + kx)) * 200 + p * 64 + lg * 16;
                    bf16x8 bfrag = *(const bf16x8*)((const char*)tile + off);
                    #pragma unroll
                    for (int mf = 0; mf < 4; ++mf)
                        acc[mf][nf] = __builtin_amdgcn_mfma_f32_16x16x32_bf16(Af[mf], bfrag, acc[mf][nf], 0, 0, 0);
                }
                #pragma unroll
                for (int mf = 0; mf < 4; ++mf) Af[mf] = Afn[mf];
            }
        }
    }

    #pragma unroll
    for (int mf = 0; mf < 4; ++mf) {
        #pragma unroll
        for (int nf = 0; nf < 4; ++nf) {
            int rowi = i0 + wv * 4 + nf;
            int col = j0 + lm;
            #pragma unroll
            for (int r = 0; r < 4; ++r) {
                int co = mf * 16 + lg * 4 + r;
                out[(((size_t)n * C_OUT + co) * HH + rowi) * WW + col] = acc[mf][nf][r];
            }
        }
    }
}

extern "C" void kernel_launch(void* const* d_in, const int* in_sizes, int n_in,
                              void* d_out, int out_size, void* d_ws, size_t ws_size,
                              hipStream_t stream) {
    (void)in_sizes; (void)n_in; (void)out_size;
    const float* x      = (const float*)d_in[0];
    const float* weight = (const float*)d_in[1];
    const float* bias   = (const float*)d_in[2];
    const float* shifts = (const float*)d_in[3];
    float* out = (float*)d_out;

    const size_t xv_elems = (size_t)NB * HH * WW * 64;     // u16 (32 MB)
    const size_t need2 = xv_elems * 2 + 110592 * 2;

    if (ws_size >= need2) {
        unsigned short* xv   = (unsigned short*)d_ws;
        unsigned short* wbuf = xv + xv_elems;
        prep_w3<<<432, 256, 0, stream>>>(weight, wbuf);
        shift_v<<<NB * HH * 2, 256, 0, stream>>>(x, shifts, xv);
        conv2b<<<1024, 256, 0, stream>>>(xv, wbuf, bias, out);
    } else {
        unsigned short* wbuf = (unsigned short*)d_ws;
        prep_w3<<<432, 256, 0, stream>>>(weight, wbuf);
        conv_f<<<1024, 256, 0, stream>>>(x, shifts, wbuf, bias, out);
    }
}